// Round 8
// baseline (373.311 us; speedup 1.0000x reference)
//
#include <hip/hip_runtime.h>
#include <hip/hip_bf16.h>

#define NR 12288
#define DIMS 256
#define TOPP 9
#define NCH 8               // main-pass col chunks (1536 cols, chunk == XCD)
#define CWM 1536
#define SMP 1536            // threshold sample width per row (E ~71 survivors)
#define PKT 32768           // bytes per packed 64-col tile

typedef __attribute__((ext_vector_type(8))) short short8v;
typedef __attribute__((ext_vector_type(4))) float f32x4;

__device__ __forceinline__ unsigned short f2bf(float f) {
    unsigned int u = __float_as_uint(f);
    u += 0x7fffu + ((u >> 16) & 1u);
    return (unsigned short)(u >> 16);
}

// Sortable key: top 18 bits = monotone-mapped float, low 14 = col (unique).
__device__ __forceinline__ unsigned packkey(float v, int col) {
    unsigned u = __float_as_uint(v);
    u ^= (unsigned)((int)u >> 31) | 0x80000000u;
    return (u & 0xFFFFC000u) | (unsigned)col;
}

// Keep 9 largest keys; replace-all-equal-mn requires ALL values distinct.
// Real keys are unique (col bits); sentinels MUST be lane-unique before any
// cross-lane merge (round-7 bug: shared sentinels -> duplicate propagation ->
// thr = 8th-largest -> o=7 rows).
__device__ __forceinline__ void top9u(unsigned (&a)[9], unsigned& mn, unsigned key) {
    if (key > mn) {
#pragma unroll
        for (int k = 0; k < 9; ++k) a[k] = (a[k] == mn) ? key : a[k];
        unsigned m = a[0];
#pragma unroll
        for (int k = 1; k < 9; ++k) m = min(m, a[k]);
        mn = m;
    }
}

// ---------- 1) normalize fp32 -> bf16 directly into packed fragment layout --
// frag addr of (col-row C, kk, lg): (C>>6)*PKT + kk*4096 + (C&63)*64 + lg*16
__global__ void k_normpack(const float* __restrict__ x, char* __restrict__ pk) {
    const int wave = threadIdx.x >> 6, lane = threadIdx.x & 63;
    const int row = blockIdx.x * 4 + wave;
    const float4 v = *(const float4*)(x + (size_t)row * DIMS + lane * 4);
    float ss = v.x * v.x + v.y * v.y + v.z * v.z + v.w * v.w;
#pragma unroll
    for (int off = 32; off > 0; off >>= 1) ss += __shfl_xor(ss, off);
    const float inv = 1.0f / fmaxf(sqrtf(ss), 1e-12f);
    ushort4 o;
    o.x = f2bf(v.x * inv); o.y = f2bf(v.y * inv);
    o.z = f2bf(v.z * inv); o.w = f2bf(v.w * inv);
    const int kk = lane >> 3, lg = (lane >> 1) & 3, sub = (lane & 1) * 8;
    *(ushort4*)(pk + (size_t)(row >> 6) * PKT + kk * 4096 + (row & 63) * 64 + lg * 16 + sub) = o;
}

// ---------- 2) k_thrS: per-row lower-bound threshold from a 1536-col sample --
// Block = 16 rows; 4 waves sample disjoint 384-col ranges. Each lane inserts
// 24 keys per r before merging (sentinels fully flushed), but lane-unique
// sentinels are used anyway.
__global__ __launch_bounds__(256, 4) void k_thrS(const char* __restrict__ pk,
                                                 float* __restrict__ thrF) {
    const int bid = blockIdx.x;
    const int w = threadIdx.x >> 6, lane = threadIdx.x & 63;
    const int l15 = lane & 15, lg = lane >> 4;
    const int R = bid * 16;
    const int base = (bid & 7) * SMP + w * 384;

    short8v aF[8];
    {
        const char* ap = pk + (size_t)(R >> 6) * PKT + ((R & 63) + l15) * 64 + lg * 16;
#pragma unroll
        for (int kk = 0; kk < 8; ++kk) aF[kk] = *(const short8v*)(ap + kk * 4096);
    }
    unsigned t9[4][9]; unsigned kmin[4];
#pragma unroll
    for (int r = 0; r < 4; ++r) {
        kmin[r] = (unsigned)(lane * 16);
#pragma unroll
        for (int k = 0; k < 9; ++k) t9[r][k] = (unsigned)(lane * 16 + k);
    }

    for (int t = 0; t < 6; ++t) {
        const int cb = base + t * 64;
        const char* tb = pk + (size_t)(cb >> 6) * PKT + l15 * 64 + lg * 16;
        f32x4 acc0 = {0.f,0.f,0.f,0.f}, acc1 = {0.f,0.f,0.f,0.f};
        f32x4 acc2 = {0.f,0.f,0.f,0.f}, acc3 = {0.f,0.f,0.f,0.f};
#pragma unroll
        for (int kk = 0; kk < 8; ++kk) {
            short8v b0 = *(const short8v*)(tb + kk * 4096);
            short8v b1 = *(const short8v*)(tb + kk * 4096 + 1024);
            short8v b2 = *(const short8v*)(tb + kk * 4096 + 2048);
            short8v b3 = *(const short8v*)(tb + kk * 4096 + 3072);
            acc0 = __builtin_amdgcn_mfma_f32_16x16x32_bf16(aF[kk], b0, acc0, 0,0,0);
            acc1 = __builtin_amdgcn_mfma_f32_16x16x32_bf16(aF[kk], b1, acc1, 0,0,0);
            acc2 = __builtin_amdgcn_mfma_f32_16x16x32_bf16(aF[kk], b2, acc2, 0,0,0);
            acc3 = __builtin_amdgcn_mfma_f32_16x16x32_bf16(aF[kk], b3, acc3, 0,0,0);
        }
        const int c0 = cb + l15;
#pragma unroll
        for (int r = 0; r < 4; ++r) {
            top9u(t9[r], kmin[r], packkey(acc0[r], c0));
            top9u(t9[r], kmin[r], packkey(acc1[r], c0 + 16));
            top9u(t9[r], kmin[r], packkey(acc2[r], c0 + 32));
            top9u(t9[r], kmin[r], packkey(acc3[r], c0 + 48));
        }
    }

    // merge over the 16 lanes (cols) sharing each row: snapshot-then-insert
#pragma unroll
    for (int off = 1; off < 16; off <<= 1) {
#pragma unroll
        for (int r = 0; r < 4; ++r) {
            unsigned o[9];
#pragma unroll
            for (int k = 0; k < 9; ++k) o[k] = (unsigned)__shfl_xor((int)t9[r][k], off);
#pragma unroll
            for (int k = 0; k < 9; ++k) top9u(t9[r], kmin[r], o[k]);
        }
    }
    __shared__ unsigned m9[4][16][9];
    if (l15 == 0) {
#pragma unroll
        for (int r = 0; r < 4; ++r)
#pragma unroll
            for (int k = 0; k < 9; ++k) m9[w][lg * 4 + r][k] = t9[r][k];
    }
    __syncthreads();
    if (threadIdx.x < 16) {
        unsigned a[9]; unsigned mn = 0;
#pragma unroll
        for (int k = 0; k < 9; ++k) a[k] = (unsigned)k;   // serial merge: distinct ok
        for (int ww = 0; ww < 4; ++ww)
#pragma unroll
            for (int k = 0; k < 9; ++k) top9u(a, mn, m9[ww][threadIdx.x][k]);
        // float whose key-floor equals mn's quantum: (v >= tF) <=> key18(v) >= mn&~0x3FFF
        const unsigned T = mn & 0xFFFFC000u;
        thrF[R + threadIdx.x] = (T & 0x80000000u) ? __uint_as_float(T ^ 0x80000000u)
                                                  : __uint_as_float(~T);
    }
}

// ---------- 3) k_mainN: full GEMM from packed (no LDS), cheap filter ----------
// Cols-split: wave q owns a 16-col strip, all 64 rows in registers.
// Survivors (E ~71/row) -> per-ROW bucket via global atomic count.
__global__ __launch_bounds__(256, 2) void k_mainN(const char* __restrict__ pk,
                                                  const float* __restrict__ thrF,
                                                  unsigned* __restrict__ bufg,
                                                  unsigned* __restrict__ cnt,
                                                  unsigned capc) {
    const int bid = blockIdx.x;
    const int chunk = bid & 7, rb = bid >> 3;     // chunk == XCD id
    const int q = threadIdx.x >> 6, lane = threadIdx.x & 63;
    const int l15 = lane & 15, lg = lane >> 4;
    const int R0 = rb * 64;

    short8v aF[4][8];
#pragma unroll
    for (int m = 0; m < 4; ++m) {
        const char* ap = pk + (size_t)rb * PKT + (m * 16 + l15) * 64 + lg * 16;
#pragma unroll
        for (int kk = 0; kk < 8; ++kk) aF[m][kk] = *(const short8v*)(ap + kk * 4096);
    }
    float tv[4][4];
#pragma unroll
    for (int m = 0; m < 4; ++m)
#pragma unroll
        for (int r = 0; r < 4; ++r) tv[m][r] = thrF[R0 + m * 16 + lg * 4 + r];

    const int chTile = chunk * (CWM / 64);

#define APPEND(M, ACC)                                                         \
    _Pragma("unroll")                                                          \
    for (int r = 0; r < 4; ++r) {                                              \
        if (ACC[r] >= tv[M][r]) {                                              \
            const int rg = R0 + (M) * 16 + lg * 4 + r;                         \
            const unsigned key = packkey(ACC[r], col);                         \
            const unsigned idx = atomicAdd(&cnt[rg], 1u);                      \
            if (idx < capc) bufg[(size_t)rg * capc + idx] = key;               \
        }                                                                      \
    }

    for (int ct = 0; ct < CWM / 64; ++ct) {
        const char* tb = pk + (size_t)(chTile + ct) * PKT + q * 1024 + l15 * 64 + lg * 16;
        short8v b0[4], b1[4];
#pragma unroll
        for (int j = 0; j < 4; ++j) b0[j] = *(const short8v*)(tb + j * 4096);
#pragma unroll
        for (int j = 0; j < 4; ++j) b1[j] = *(const short8v*)(tb + (4 + j) * 4096);
        f32x4 acc0 = {0.f,0.f,0.f,0.f}, acc1 = {0.f,0.f,0.f,0.f};
        f32x4 acc2 = {0.f,0.f,0.f,0.f}, acc3 = {0.f,0.f,0.f,0.f};
#pragma unroll
        for (int j = 0; j < 4; ++j) {
            acc0 = __builtin_amdgcn_mfma_f32_16x16x32_bf16(aF[0][j], b0[j], acc0, 0,0,0);
            acc1 = __builtin_amdgcn_mfma_f32_16x16x32_bf16(aF[1][j], b0[j], acc1, 0,0,0);
            acc2 = __builtin_amdgcn_mfma_f32_16x16x32_bf16(aF[2][j], b0[j], acc2, 0,0,0);
            acc3 = __builtin_amdgcn_mfma_f32_16x16x32_bf16(aF[3][j], b0[j], acc3, 0,0,0);
        }
#pragma unroll
        for (int j = 0; j < 4; ++j) {
            acc0 = __builtin_amdgcn_mfma_f32_16x16x32_bf16(aF[0][4+j], b1[j], acc0, 0,0,0);
            acc1 = __builtin_amdgcn_mfma_f32_16x16x32_bf16(aF[1][4+j], b1[j], acc1, 0,0,0);
            acc2 = __builtin_amdgcn_mfma_f32_16x16x32_bf16(aF[2][4+j], b1[j], acc2, 0,0,0);
            acc3 = __builtin_amdgcn_mfma_f32_16x16x32_bf16(aF[3][4+j], b1[j], acc3, 0,0,0);
        }
        const int col = chunk * CWM + ct * 64 + q * 16 + l15;
        APPEND(0, acc0)
        APPEND(1, acc1)
        APPEND(2, acc2)
        APPEND(3, acc3)
    }
#undef APPEND
}

// ---------- 4) k_sel: exact per-row 9th key over survivors + degrees ----------
// 16 lanes per row, strided coalesced reads, butterfly merge with LANE-UNIQUE
// sentinels (the round-7 fix).
__global__ void k_sel(const unsigned* __restrict__ bufg, const unsigned* __restrict__ cnt,
                      unsigned capc, unsigned* __restrict__ dd, unsigned* __restrict__ gg) {
    const int w = threadIdx.x >> 6, lane = threadIdx.x & 63;
    const int l15 = lane & 15, lg = lane >> 4;
    const int row = blockIdx.x * 16 + w * 4 + lg;

    const unsigned n = min(cnt[row], capc);
    const unsigned* bp = bufg + (size_t)row * capc;

    unsigned a[9]; unsigned mn = (unsigned)(l15 * 16);
#pragma unroll
    for (int k = 0; k < 9; ++k) a[k] = (unsigned)(l15 * 16 + k);   // lane-unique
    for (unsigned s = l15; s < n; s += 16) top9u(a, mn, bp[s]);
#pragma unroll
    for (int off = 1; off < 16; off <<= 1) {
        unsigned o[9];
#pragma unroll
        for (int k = 0; k < 9; ++k) o[k] = (unsigned)__shfl_xor((int)a[k], off);
#pragma unroll
        for (int k = 0; k < 9; ++k) top9u(a, mn, o[k]);
    }
    const unsigned thr = mn;   // exact 9th-largest key of the row (diag incl.)
    unsigned o = 0;
    for (unsigned s = l15; s < n; s += 16) {
        const unsigned key = bp[s];
        const int col = (int)(key & 16383u);
        if (key >= thr && col != row) { ++o; atomicAdd(&gg[col], 1u); }
    }
#pragma unroll
    for (int off = 1; off < 16; off <<= 1) o += (unsigned)__shfl_xor((int)o, off);
    if (l15 == 0) dd[row] = o;
}

// ---------- 5) wsum = sum_i o*d + g*d - 2o, d = max(o,1) ----------
__global__ void k_wsum(const unsigned* __restrict__ dd, const unsigned* __restrict__ gg,
                       unsigned long long* __restrict__ wsum) {
    const int i = blockIdx.x * 256 + threadIdx.x;
    const unsigned long long o = dd[i];
    const unsigned long long g = gg[i];
    const unsigned long long d = o ? o : 1ull;
    unsigned long long acc = o * d + g * d - 2ull * o;
#pragma unroll
    for (int off = 32; off > 0; off >>= 1) acc += __shfl_xor(acc, off);
    if ((threadIdx.x & 63) == 0 && acc) atomicAdd(wsum, acc);
}

// ---------- 6) finalize ----------
__global__ void k_fin(const unsigned long long* __restrict__ wsum, float* __restrict__ out) {
    out[0] = (float)((double)*wsum * (0.01 / ((double)NR * (double)NR)));
}

extern "C" void kernel_launch(void* const* d_in, const int* in_sizes, int n_in,
                              void* d_out, int out_size, void* d_ws, size_t ws_size,
                              hipStream_t stream) {
    const float* x = (const float*)d_in[0];
    float* out = (float*)d_out;
    char* ws = (char*)d_ws;

    size_t off = 0;
    char* pk = ws + off;                               off += (size_t)NR * DIMS * 2;   // 6.29 MB
    float* thrF = (float*)(ws + off);                  off += (size_t)NR * 4;
    unsigned* cnt = (unsigned*)(ws + off);             off += (size_t)NR * 4;
    unsigned* dd = (unsigned*)(ws + off);              off += (size_t)NR * 4;
    unsigned* gg = (unsigned*)(ws + off);              off += (size_t)NR * 4;
    unsigned long long* wsum = (unsigned long long*)(ws + off); off += 64;
    unsigned* bufg = (unsigned*)(ws + off);
    // per-row survivor capacity from remaining workspace (runtime-constant)
    size_t rem = (ws_size > off) ? (ws_size - off) / ((size_t)NR * 4) : 64;
    unsigned capc = (unsigned)(rem < 64 ? 64 : (rem > 512 ? 512 : rem));

    hipMemsetAsync(cnt, 0, (size_t)NR * 4, stream);
    hipMemsetAsync(gg, 0, (size_t)NR * 4, stream);
    hipMemsetAsync(wsum, 0, 8, stream);

    k_normpack<<<NR / 4, 256, 0, stream>>>(x, pk);
    k_thrS<<<NR / 16, 256, 0, stream>>>(pk, thrF);
    k_mainN<<<(NR / 64) * NCH, 256, 0, stream>>>(pk, thrF, bufg, cnt, capc);
    k_sel<<<NR / 16, 256, 0, stream>>>(bufg, cnt, capc, dd, gg);
    k_wsum<<<NR / 256, 256, 0, stream>>>(dd, gg, wsum);
    k_fin<<<1, 1, 0, stream>>>(wsum, out);
}

// Round 9
// 349.623 us; speedup vs baseline: 1.0678x; 1.0678x over previous
//
#include <hip/hip_runtime.h>
#include <hip/hip_bf16.h>

#define NR 12288
#define DIMS 256
#define TOPP 9
#define NCH 8               // main-pass col chunks (1536 cols, chunk == XCD)
#define CWM 1536
#define SMP 1536            // threshold sample width per row (E ~71 survivors)
#define PKT 32768           // bytes per packed 64-col tile

typedef __attribute__((ext_vector_type(8))) short short8v;
typedef __attribute__((ext_vector_type(4))) float f32x4;

__device__ __forceinline__ unsigned short f2bf(float f) {
    unsigned int u = __float_as_uint(f);
    u += 0x7fffu + ((u >> 16) & 1u);
    return (unsigned short)(u >> 16);
}

// Sortable key: top 18 bits = monotone-mapped float, low 14 = col (unique).
__device__ __forceinline__ unsigned packkey(float v, int col) {
    unsigned u = __float_as_uint(v);
    u ^= (unsigned)((int)u >> 31) | 0x80000000u;
    return (u & 0xFFFFC000u) | (unsigned)col;
}

// Keep 9 largest keys; replace-all-equal-mn requires ALL values distinct.
// Sentinels must be lane-unique before any cross-lane merge (round-7 lesson).
__device__ __forceinline__ void top9u(unsigned (&a)[9], unsigned& mn, unsigned key) {
    if (key > mn) {
#pragma unroll
        for (int k = 0; k < 9; ++k) a[k] = (a[k] == mn) ? key : a[k];
        unsigned m = a[0];
#pragma unroll
        for (int k = 1; k < 9; ++k) m = min(m, a[k]);
        mn = m;
    }
}

// ---------- 1) normalize fp32 -> bf16 directly into packed fragment layout --
// frag addr of (col-row C, kk, lg): (C>>6)*PKT + kk*4096 + (C&63)*64 + lg*16
__global__ void k_normpack(const float* __restrict__ x, char* __restrict__ pk) {
    const int wave = threadIdx.x >> 6, lane = threadIdx.x & 63;
    const int row = blockIdx.x * 4 + wave;
    const float4 v = *(const float4*)(x + (size_t)row * DIMS + lane * 4);
    float ss = v.x * v.x + v.y * v.y + v.z * v.z + v.w * v.w;
#pragma unroll
    for (int off = 32; off > 0; off >>= 1) ss += __shfl_xor(ss, off);
    const float inv = 1.0f / fmaxf(sqrtf(ss), 1e-12f);
    ushort4 o;
    o.x = f2bf(v.x * inv); o.y = f2bf(v.y * inv);
    o.z = f2bf(v.z * inv); o.w = f2bf(v.w * inv);
    const int kk = lane >> 3, lg = (lane >> 1) & 3, sub = (lane & 1) * 8;
    *(ushort4*)(pk + (size_t)(row >> 6) * PKT + kk * 4096 + (row & 63) * 64 + lg * 16 + sub) = o;
}

// ---------- 2) k_thrS: per-row lower-bound threshold from a 1536-col sample --
__global__ __launch_bounds__(256, 4) void k_thrS(const char* __restrict__ pk,
                                                 float* __restrict__ thrF) {
    const int bid = blockIdx.x;
    const int w = threadIdx.x >> 6, lane = threadIdx.x & 63;
    const int l15 = lane & 15, lg = lane >> 4;
    const int R = bid * 16;
    const int base = (bid & 7) * SMP + w * 384;

    short8v aF[8];
    {
        const char* ap = pk + (size_t)(R >> 6) * PKT + ((R & 63) + l15) * 64 + lg * 16;
#pragma unroll
        for (int kk = 0; kk < 8; ++kk) aF[kk] = *(const short8v*)(ap + kk * 4096);
    }
    unsigned t9[4][9]; unsigned kmin[4];
#pragma unroll
    for (int r = 0; r < 4; ++r) {
        kmin[r] = (unsigned)(lane * 16);
#pragma unroll
        for (int k = 0; k < 9; ++k) t9[r][k] = (unsigned)(lane * 16 + k);   // lane-unique
    }

    for (int t = 0; t < 6; ++t) {
        const int cb = base + t * 64;
        const char* tb = pk + (size_t)(cb >> 6) * PKT + l15 * 64 + lg * 16;
        f32x4 acc0 = {0.f,0.f,0.f,0.f}, acc1 = {0.f,0.f,0.f,0.f};
        f32x4 acc2 = {0.f,0.f,0.f,0.f}, acc3 = {0.f,0.f,0.f,0.f};
#pragma unroll
        for (int kk = 0; kk < 8; ++kk) {
            short8v b0 = *(const short8v*)(tb + kk * 4096);
            short8v b1 = *(const short8v*)(tb + kk * 4096 + 1024);
            short8v b2 = *(const short8v*)(tb + kk * 4096 + 2048);
            short8v b3 = *(const short8v*)(tb + kk * 4096 + 3072);
            acc0 = __builtin_amdgcn_mfma_f32_16x16x32_bf16(aF[kk], b0, acc0, 0,0,0);
            acc1 = __builtin_amdgcn_mfma_f32_16x16x32_bf16(aF[kk], b1, acc1, 0,0,0);
            acc2 = __builtin_amdgcn_mfma_f32_16x16x32_bf16(aF[kk], b2, acc2, 0,0,0);
            acc3 = __builtin_amdgcn_mfma_f32_16x16x32_bf16(aF[kk], b3, acc3, 0,0,0);
        }
        const int c0 = cb + l15;
#pragma unroll
        for (int r = 0; r < 4; ++r) {
            top9u(t9[r], kmin[r], packkey(acc0[r], c0));
            top9u(t9[r], kmin[r], packkey(acc1[r], c0 + 16));
            top9u(t9[r], kmin[r], packkey(acc2[r], c0 + 32));
            top9u(t9[r], kmin[r], packkey(acc3[r], c0 + 48));
        }
    }

    // merge over the 16 lanes (cols) sharing each row: snapshot-then-insert
#pragma unroll
    for (int off = 1; off < 16; off <<= 1) {
#pragma unroll
        for (int r = 0; r < 4; ++r) {
            unsigned o[9];
#pragma unroll
            for (int k = 0; k < 9; ++k) o[k] = (unsigned)__shfl_xor((int)t9[r][k], off);
#pragma unroll
            for (int k = 0; k < 9; ++k) top9u(t9[r], kmin[r], o[k]);
        }
    }
    __shared__ unsigned m9[4][16][9];
    if (l15 == 0) {
#pragma unroll
        for (int r = 0; r < 4; ++r)
#pragma unroll
            for (int k = 0; k < 9; ++k) m9[w][lg * 4 + r][k] = t9[r][k];
    }
    __syncthreads();
    if (threadIdx.x < 16) {
        unsigned a[9]; unsigned mn = 0;
#pragma unroll
        for (int k = 0; k < 9; ++k) a[k] = (unsigned)k;   // serial: distinct ok
        for (int ww = 0; ww < 4; ++ww)
#pragma unroll
            for (int k = 0; k < 9; ++k) top9u(a, mn, m9[ww][threadIdx.x][k]);
        // float whose key-floor equals mn's quantum: (v >= tF) <=> key18(v) >= mn&~0x3FFF
        const unsigned T = mn & 0xFFFFC000u;
        thrF[R + threadIdx.x] = (T & 0x80000000u) ? __uint_as_float(T ^ 0x80000000u)
                                                  : __uint_as_float(~T);
    }
}

// ---------- 3) k_mainN: full GEMM from packed, reg-dbuf B, pinned A ----------
// Cols-split: wave q owns a 16-col strip, all 64 rows in registers.
// Round-8 lesson: compiler SANK the 128-VGPR aF array into the loop (VGPR=112
// reported) -> L2-latency-bound. Pin aF live with empty asm each iteration,
// and double-buffer B fragments so next-tile loads overlap current MFMAs.
__global__ __launch_bounds__(256, 2) void k_mainN(const char* __restrict__ pk,
                                                  const float* __restrict__ thrF,
                                                  unsigned* __restrict__ bufg,
                                                  unsigned* __restrict__ cnt,
                                                  unsigned capc) {
    const int bid = blockIdx.x;
    const int chunk = bid & 7, rb = bid >> 3;     // chunk == XCD id
    const int q = threadIdx.x >> 6, lane = threadIdx.x & 63;
    const int l15 = lane & 15, lg = lane >> 4;
    const int R0 = rb * 64;

    short8v aF0[8], aF1[8], aF2[8], aF3[8];
    {
        const char* ap = pk + (size_t)rb * PKT + l15 * 64 + lg * 16;
#pragma unroll
        for (int kk = 0; kk < 8; ++kk) {
            aF0[kk] = *(const short8v*)(ap + kk * 4096);
            aF1[kk] = *(const short8v*)(ap + kk * 4096 + 16 * 64);
            aF2[kk] = *(const short8v*)(ap + kk * 4096 + 32 * 64);
            aF3[kk] = *(const short8v*)(ap + kk * 4096 + 48 * 64);
        }
    }
    float tv[4][4];
#pragma unroll
    for (int m = 0; m < 4; ++m)
#pragma unroll
        for (int r = 0; r < 4; ++r) tv[m][r] = thrF[R0 + m * 16 + lg * 4 + r];

    const int NCT = CWM / 64;                     // 24
    const char* tbase = pk + (size_t)(chunk * NCT) * PKT + q * 1024 + l15 * 64 + lg * 16;

#define PIN8(A) asm volatile("" :: "v"(A[0]), "v"(A[1]), "v"(A[2]), "v"(A[3]), \
                                   "v"(A[4]), "v"(A[5]), "v"(A[6]), "v"(A[7]));

#define LOADB(DST, CT)                                                         \
    {                                                                          \
        const char* tb_ = tbase + (size_t)(CT) * PKT;                          \
        _Pragma("unroll")                                                      \
        for (int j = 0; j < 8; ++j) DST[j] = *(const short8v*)(tb_ + j * 4096);\
    }

#define COMPUTE(B, CT)                                                         \
    {                                                                          \
        f32x4 acc0 = {0.f,0.f,0.f,0.f}, acc1 = {0.f,0.f,0.f,0.f};              \
        f32x4 acc2 = {0.f,0.f,0.f,0.f}, acc3 = {0.f,0.f,0.f,0.f};              \
        _Pragma("unroll")                                                      \
        for (int j = 0; j < 8; ++j) {                                          \
            acc0 = __builtin_amdgcn_mfma_f32_16x16x32_bf16(aF0[j], B[j], acc0, 0,0,0); \
            acc1 = __builtin_amdgcn_mfma_f32_16x16x32_bf16(aF1[j], B[j], acc1, 0,0,0); \
            acc2 = __builtin_amdgcn_mfma_f32_16x16x32_bf16(aF2[j], B[j], acc2, 0,0,0); \
            acc3 = __builtin_amdgcn_mfma_f32_16x16x32_bf16(aF3[j], B[j], acc3, 0,0,0); \
        }                                                                      \
        const int col = chunk * CWM + (CT) * 64 + q * 16 + l15;                \
        APPEND(0, acc0) APPEND(1, acc1) APPEND(2, acc2) APPEND(3, acc3)        \
    }

#define APPEND(M, ACC)                                                         \
    _Pragma("unroll")                                                          \
    for (int r = 0; r < 4; ++r) {                                              \
        if (ACC[r] >= tv[M][r]) {                                              \
            const int rg = R0 + (M) * 16 + lg * 4 + r;                         \
            const unsigned key = packkey(ACC[r], col);                         \
            const unsigned idx = atomicAdd(&cnt[rg], 1u);                      \
            if (idx < capc) bufg[(size_t)rg * capc + idx] = key;               \
        }                                                                      \
    }

    short8v bA[8], bB[8];
    LOADB(bA, 0)
    for (int ctp = 0; ctp < NCT / 2; ++ctp) {
        PIN8(aF0) PIN8(aF1) PIN8(aF2) PIN8(aF3)
        const int ct0 = 2 * ctp;
        LOADB(bB, ct0 + 1)          // issue next-tile loads before MFMA burst
        COMPUTE(bA, ct0)
        if (ctp < NCT / 2 - 1) LOADB(bA, ct0 + 2)
        COMPUTE(bB, ct0 + 1)
    }
#undef APPEND
#undef COMPUTE
#undef LOADB
#undef PIN8
}

// ---------- 4) k_sel: exact per-row 9th key over survivors + degrees ----------
// 16 lanes per row, strided reads, butterfly merge with lane-unique sentinels.
__global__ void k_sel(const unsigned* __restrict__ bufg, const unsigned* __restrict__ cnt,
                      unsigned capc, unsigned* __restrict__ dd, unsigned* __restrict__ gg) {
    const int w = threadIdx.x >> 6, lane = threadIdx.x & 63;
    const int l15 = lane & 15, lg = lane >> 4;
    const int row = blockIdx.x * 16 + w * 4 + lg;

    const unsigned n = min(cnt[row], capc);
    const unsigned* bp = bufg + (size_t)row * capc;

    unsigned a[9]; unsigned mn = (unsigned)(l15 * 16);
#pragma unroll
    for (int k = 0; k < 9; ++k) a[k] = (unsigned)(l15 * 16 + k);   // lane-unique
    for (unsigned s = l15; s < n; s += 16) top9u(a, mn, bp[s]);
#pragma unroll
    for (int off = 1; off < 16; off <<= 1) {
        unsigned o[9];
#pragma unroll
        for (int k = 0; k < 9; ++k) o[k] = (unsigned)__shfl_xor((int)a[k], off);
#pragma unroll
        for (int k = 0; k < 9; ++k) top9u(a, mn, o[k]);
    }
    const unsigned thr = mn;   // exact 9th-largest key of the row (diag incl.)
    unsigned o = 0;
    for (unsigned s = l15; s < n; s += 16) {
        const unsigned key = bp[s];
        const int col = (int)(key & 16383u);
        if (key >= thr && col != row) { ++o; atomicAdd(&gg[col], 1u); }
    }
#pragma unroll
    for (int off = 1; off < 16; off <<= 1) o += (unsigned)__shfl_xor((int)o, off);
    if (l15 == 0) dd[row] = o;
}

// ---------- 5) wsum = sum_i o*d + g*d - 2o, d = max(o,1) ----------
__global__ void k_wsum(const unsigned* __restrict__ dd, const unsigned* __restrict__ gg,
                       unsigned long long* __restrict__ wsum) {
    const int i = blockIdx.x * 256 + threadIdx.x;
    const unsigned long long o = dd[i];
    const unsigned long long g = gg[i];
    const unsigned long long d = o ? o : 1ull;
    unsigned long long acc = o * d + g * d - 2ull * o;
#pragma unroll
    for (int off = 32; off > 0; off >>= 1) acc += __shfl_xor(acc, off);
    if ((threadIdx.x & 63) == 0 && acc) atomicAdd(wsum, acc);
}

// ---------- 6) finalize ----------
__global__ void k_fin(const unsigned long long* __restrict__ wsum, float* __restrict__ out) {
    out[0] = (float)((double)*wsum * (0.01 / ((double)NR * (double)NR)));
}

extern "C" void kernel_launch(void* const* d_in, const int* in_sizes, int n_in,
                              void* d_out, int out_size, void* d_ws, size_t ws_size,
                              hipStream_t stream) {
    const float* x = (const float*)d_in[0];
    float* out = (float*)d_out;
    char* ws = (char*)d_ws;

    size_t off = 0;
    char* pk = ws + off;                               off += (size_t)NR * DIMS * 2;   // 6.29 MB
    float* thrF = (float*)(ws + off);                  off += (size_t)NR * 4;
    unsigned* cnt = (unsigned*)(ws + off);             off += (size_t)NR * 4;
    unsigned* dd = (unsigned*)(ws + off);              off += (size_t)NR * 4;
    unsigned* gg = (unsigned*)(ws + off);              off += (size_t)NR * 4;
    unsigned long long* wsum = (unsigned long long*)(ws + off); off += 64;
    unsigned* bufg = (unsigned*)(ws + off);
    // per-row survivor capacity from remaining workspace (runtime-constant)
    size_t rem = (ws_size > off) ? (ws_size - off) / ((size_t)NR * 4) : 64;
    unsigned capc = (unsigned)(rem < 64 ? 64 : (rem > 512 ? 512 : rem));

    hipMemsetAsync(cnt, 0, (size_t)NR * 4, stream);
    hipMemsetAsync(gg, 0, (size_t)NR * 4, stream);
    hipMemsetAsync(wsum, 0, 8, stream);

    k_normpack<<<NR / 4, 256, 0, stream>>>(x, pk);
    k_thrS<<<NR / 16, 256, 0, stream>>>(pk, thrF);
    k_mainN<<<(NR / 64) * NCH, 256, 0, stream>>>(pk, thrF, bufg, cnt, capc);
    k_sel<<<NR / 16, 256, 0, stream>>>(bufg, cnt, capc, dd, gg);
    k_wsum<<<NR / 256, 256, 0, stream>>>(dd, gg, wsum);
    k_fin<<<1, 1, 0, stream>>>(wsum, out);
}